// Round 11
// baseline (136.071 us; speedup 1.0000x reference)
//
#include <hip/hip_runtime.h>
#include <stdint.h>

#define IN_DIM  4096
#define OUT_DIM 4096
#define BATCH   4096
#define NACT    32

typedef float          f32x4  __attribute__((ext_vector_type(4)));
typedef unsigned short u16x4  __attribute__((ext_vector_type(4)));

// round-to-nearest f32 -> bf16
__device__ inline unsigned short f2bf(float f) {
    unsigned u = __float_as_uint(f);
    u += 0x7FFF + ((u >> 16) & 1);
    return (unsigned short)(u >> 16);
}

// ---------------------------------------------------------------------------
// Fused prep kernel (measured ~27us ~= its 160MB/6.3TB/s roofline).
//   blocks [0, OUT_DIM)              : compress mask+weight -> idx/w tables
//   blocks [OUT_DIM, OUT_DIM+4096)   : transpose x -> xT bf16 [IN_DIM][BATCH]
// ---------------------------------------------------------------------------
__global__ __launch_bounds__(256)
void prep_kernel(const float* __restrict__ weight,
                 const int*   __restrict__ mask,
                 const float* __restrict__ x,
                 int*         __restrict__ idx_tab,
                 float*       __restrict__ w_tab,
                 unsigned short* __restrict__ xT) {
    __shared__ float tile[64][65];        // transpose tile; aliased as scan[]
    int* scan = (int*)&tile[0][0];
    const int t = threadIdx.x;

    if (blockIdx.x < OUT_DIM) {
        // ---- compress: one block per output row ----
        const int o = blockIdx.x;
        const int* mrow = mask + (size_t)o * IN_DIM;
        const int  base = t * 16;

        int m[16];
        const int4* m4 = (const int4*)(mrow + base);
        #pragma unroll
        for (int j = 0; j < 4; ++j) {
            int4 v = m4[j];
            m[j*4+0] = v.x; m[j*4+1] = v.y; m[j*4+2] = v.z; m[j*4+3] = v.w;
        }
        int c = 0;
        #pragma unroll
        for (int j = 0; j < 16; ++j) c += (m[j] != 0);

        scan[t] = c;
        __syncthreads();
        for (int off = 1; off < 256; off <<= 1) {
            int add = (t >= off) ? scan[t - off] : 0;
            __syncthreads();
            scan[t] += add;
            __syncthreads();
        }
        int pos = scan[t] - c;            // exclusive prefix
        for (int j = 0; j < 16; ++j) {
            if (m[j] != 0) {
                int idx = base + j;
                idx_tab[o * NACT + pos] = idx;
                w_tab [o * NACT + pos] = weight[(size_t)o * IN_DIM + idx];
                ++pos;
            }
        }
    } else {
        // ---- transpose + bf16 quantize: 64x64 tile ----
        const int q  = blockIdx.x - OUT_DIM;
        const int bi = q & 63;            // batch tile
        const int bj = q >> 6;            // in-dim tile
        {
            const int c  = (t & 15) * 4;
            const int r0 = t >> 4;
            #pragma unroll
            for (int p = 0; p < 4; ++p) {
                int r = r0 + p * 16;
                float4 v = *(const float4*)(x + (size_t)(bi*64 + r) * IN_DIM + bj*64 + c);
                tile[r][c+0] = v.x; tile[r][c+1] = v.y;
                tile[r][c+2] = v.z; tile[r][c+3] = v.w;
            }
        }
        __syncthreads();
        {
            const int b4 = (t & 15) * 4;
            const int j0 = t >> 4;
            #pragma unroll
            for (int p = 0; p < 4; ++p) {
                int j = j0 + p * 16;
                u16x4 v = { f2bf(tile[b4+0][j]), f2bf(tile[b4+1][j]),
                            f2bf(tile[b4+2][j]), f2bf(tile[b4+3][j]) };
                *(u16x4*)(xT + (size_t)(bj*64 + j) * BATCH + bi*64 + b4) = v;
            }
        }
    }
}

// ---------------------------------------------------------------------------
// Main sparse matmul.
// Block = 128 threads = 2 waves; wave w owns outputs o0+8w..o0+8w+7,
// lane l owns batches 4l..4l+3 of the slab -> thread = 4 batches x 8 outputs.
// Gathers are uint2 (dwordx2) loads: ONE load serves FOUR batches ->
// 256 wave-load instrs/thread (half of r10's 512; r8 proved halving the
// load count is the lever while VMEM-issue/latency-bound), 512 B/wave-load.
// Slab = 256 batches x 4096 rows x 2B = 2 MB (proven L2-resident,
// FETCH ~= compulsory r8/r10); SALU row addressing via readfirstlane
// (r10: ~0 VALU per gather). o fully unrolled -> static acc indexing.
// Store: nt + two-pass LDS restage L[128][17] (8.7 KB; proven r10):
// full 64B lines, write stream bypasses L2 so the slab stays resident
// (r9 proved plain stores re-pollute: FETCH 36->68 MB).
// Grid = 16 slabs x 256 o-tiles; swizzle: each XCD sweeps o-tiles slab-major.
// Static occupancy: 16 blocks/CU (grid) x 2 waves = 32 waves/CU.
// ---------------------------------------------------------------------------
__global__ __launch_bounds__(128)
void spmm_kernel(const unsigned short* __restrict__ xT,
                 const int*   __restrict__ idx_tab,
                 const float* __restrict__ w_tab,
                 const float* __restrict__ bias,
                 float*       __restrict__ out) {
    const int t   = threadIdx.x;          // 0..127
    const int wv  = t >> 6;               // wave id 0/1
    const int l   = t & 63;               // lane
    const int bid = blockIdx.x;           // 4096 blocks
    const int v    = (bid & 7) * 512 + (bid >> 3);   // bijective XCD swizzle
    const int slab = v >> 8;              // 0..15 (slab-major per XCD)
    const int ot   = v & 255;             // o-tile minor
    const int o0   = ot * 16;
    const int ow   = o0 + wv * 8;         // this wave's 8 outputs
    const int b0   = slab * 256;          // slab batch base

    const uint2* xTq = (const uint2*)xT;  // 4 bf16 per uint2
    const int colq = (b0 >> 2) + l;       // this lane's uint2 column

    float acc[8][4];
    #pragma unroll
    for (int o = 0; o < 8; ++o)
        #pragma unroll
        for (int j = 0; j < 4; ++j) acc[o][j] = 0.f;

    #pragma unroll
    for (int o = 0; o < 8; ++o) {
        const int*   ip = idx_tab + (size_t)(ow + o) * NACT;   // wave-uniform
        const float* wp = w_tab   + (size_t)(ow + o) * NACT;   // -> s_load
        #pragma unroll
        for (int k = 0; k < NACT; ++k) {
            int row = __builtin_amdgcn_readfirstlane(ip[k]);   // SGPR row base
            uint2 u = xTq[(size_t)row * (BATCH/4) + colq];     // saddr + voff
            float wk = wp[k];
            acc[o][0] = fmaf(wk, __uint_as_float(u.x << 16),         acc[o][0]);
            acc[o][1] = fmaf(wk, __uint_as_float(u.x & 0xFFFF0000u), acc[o][1]);
            acc[o][2] = fmaf(wk, __uint_as_float(u.y << 16),         acc[o][2]);
            acc[o][3] = fmaf(wk, __uint_as_float(u.y & 0xFFFF0000u), acc[o][3]);
        }
        const float bo = bias[ow + o];
        #pragma unroll
        for (int j = 0; j < 4; ++j) acc[o][j] -= bo;
    }

    // ---- two-pass restage through LDS for full-line nt stores ----
    __shared__ float L[128 * 17];         // 8.7 KB: half-slab at a time
    #pragma unroll
    for (int h = 0; h < 2; ++h) {
        if ((l >> 5) == h) {              // lanes whose batches fall in half h
            const int r0 = (l & 31) * 4;  // row within half-slab
            #pragma unroll
            for (int j = 0; j < 4; ++j)
                #pragma unroll
                for (int o = 0; o < 8; ++o)
                    L[(r0 + j) * 17 + wv * 8 + o] = acc[o][j];
        }
        __syncthreads();
        #pragma unroll
        for (int p = 0; p < 4; ++p) {
            int s = t + p * 128;          // 0..511 sublines
            int r = s >> 2;               // 0..127
            int c = (s & 3) * 4;          // 16B sub-line
            f32x4 rv = { L[r*17 + c+0], L[r*17 + c+1],
                         L[r*17 + c+2], L[r*17 + c+3] };
            __builtin_nontemporal_store(rv,
                (f32x4*)(out + (size_t)(b0 + h*128 + r) * OUT_DIM + o0 + c));
        }
        __syncthreads();                  // L reused by next pass
    }
}

// ---------------------------------------------------------------------------
// Fallback A (ws >= table only): gathers from x directly (uncoalesced, correct).
// ---------------------------------------------------------------------------
__global__ __launch_bounds__(256)
void spmm_noT_kernel(const float* __restrict__ x,
                     const int*   __restrict__ idx_tab,
                     const float* __restrict__ w_tab,
                     const float* __restrict__ bias,
                     float*       __restrict__ out) {
    const int t   = threadIdx.x;
    const int bid = blockIdx.x;           // 4096 blocks
    const int slab = bid >> 8;
    const int ot   = bid & 255;
    const int o0   = ot * 16;
    const int b    = slab * 256 + t;

    float acc[16];
    #pragma unroll 1
    for (int o = 0; o < 16; ++o) {
        const int*   ip = idx_tab + (size_t)(o0 + o) * NACT;
        const float* wp = w_tab   + (size_t)(o0 + o) * NACT;
        float a = 0.f;
        for (int k = 0; k < NACT; ++k)
            a = fmaf(wp[k], x[(size_t)b * IN_DIM + ip[k]], a);
        acc[o] = a - bias[o0 + o];
    }
    float* op = out + (size_t)b * OUT_DIM + o0;
    #pragma unroll
    for (int q = 0; q < 4; ++q) {
        float4 r; r.x = acc[q*4+0]; r.y = acc[q*4+1];
                  r.z = acc[q*4+2]; r.w = acc[q*4+3];
        *(float4*)(op + q*4) = r;
    }
}

// ---------------------------------------------------------------------------
// Fallback B (tiny ws): block per output row; inline compress into LDS.
// ---------------------------------------------------------------------------
__global__ __launch_bounds__(256)
void naive_kernel(const float* __restrict__ x,
                  const float* __restrict__ weight,
                  const float* __restrict__ bias,
                  const int*   __restrict__ mask,
                  float*       __restrict__ out) {
    const int o = blockIdx.x;
    const int t = threadIdx.x;
    __shared__ int   scan[256];
    __shared__ int   sidx[NACT];
    __shared__ float sw[NACT];

    const int* mrow = mask + (size_t)o * IN_DIM;
    const int  base = t * 16;
    int c = 0;
    #pragma unroll
    for (int j = 0; j < 16; ++j) c += (mrow[base + j] != 0);
    scan[t] = c;
    __syncthreads();
    for (int off = 1; off < 256; off <<= 1) {
        int add = (t >= off) ? scan[t - off] : 0;
        __syncthreads();
        scan[t] += add;
        __syncthreads();
    }
    int pos = scan[t] - c;
    for (int j = 0; j < 16; ++j) {
        if (mrow[base + j] != 0) {
            sidx[pos] = base + j;
            sw[pos]   = weight[(size_t)o * IN_DIM + base + j];
            ++pos;
        }
    }
    __syncthreads();
    const float bo = bias[o];
    for (int b = t; b < BATCH; b += 256) {
        float a = 0.f;
        #pragma unroll
        for (int k = 0; k < NACT; ++k)
            a = fmaf(sw[k], x[(size_t)b * IN_DIM + sidx[k]], a);
        out[(size_t)b * OUT_DIM + o] = a - bo;
    }
}

// ---------------------------------------------------------------------------
extern "C" void kernel_launch(void* const* d_in, const int* in_sizes, int n_in,
                              void* d_out, int out_size, void* d_ws, size_t ws_size,
                              hipStream_t stream) {
    const float* x      = (const float*)d_in[0];
    const float* weight = (const float*)d_in[1];
    const float* bias   = (const float*)d_in[2];
    const int*   mask   = (const int*)  d_in[3];
    float* out = (float*)d_out;

    const size_t TAB_BYTES  = (size_t)OUT_DIM * NACT * (sizeof(int) + sizeof(float)); // 1 MB
    const size_t XT_BYTES   = (size_t)IN_DIM * BATCH * sizeof(unsigned short);        // 32 MB
    const size_t NEED_FULL  = TAB_BYTES + XT_BYTES;

    if (ws_size >= NEED_FULL) {
        int*   idx_tab = (int*)d_ws;
        float* w_tab   = (float*)((char*)d_ws + (size_t)OUT_DIM * NACT * sizeof(int));
        unsigned short* xT = (unsigned short*)((char*)d_ws + TAB_BYTES);

        prep_kernel<<<OUT_DIM + (BATCH/64)*(IN_DIM/64), 256, 0, stream>>>(
            weight, mask, x, idx_tab, w_tab, xT);
        spmm_kernel<<<4096, 128, 0, stream>>>(xT, idx_tab, w_tab, bias, out);
    } else if (ws_size >= TAB_BYTES) {
        int*   idx_tab = (int*)d_ws;
        float* w_tab   = (float*)((char*)d_ws + (size_t)OUT_DIM * NACT * sizeof(int));
        prep_kernel<<<OUT_DIM, 256, 0, stream>>>(
            weight, mask, x, idx_tab, w_tab, (unsigned short*)nullptr);
        spmm_noT_kernel<<<4096, 256, 0, stream>>>(x, idx_tab, w_tab, bias, out);
    } else {
        naive_kernel<<<OUT_DIM, 256, 0, stream>>>(x, weight, bias, mask, out);
    }
}

// Round 12
// 93.818 us; speedup vs baseline: 1.4504x; 1.4504x over previous
//
#include <hip/hip_runtime.h>
#include <stdint.h>

#define IN_DIM  4096
#define OUT_DIM 4096
#define BATCH   4096
#define NACT    32

typedef float          f32x4  __attribute__((ext_vector_type(4)));
typedef unsigned short u16x4  __attribute__((ext_vector_type(4)));

// round-to-nearest f32 -> bf16
__device__ inline unsigned short f2bf(float f) {
    unsigned u = __float_as_uint(f);
    u += 0x7FFF + ((u >> 16) & 1);
    return (unsigned short)(u >> 16);
}

// ---------------------------------------------------------------------------
// Fused prep kernel (measured ~27us ~= its ~170MB roofline).
//   blocks [0, OUT_DIM)              : compress mask+weight -> tables
//   blocks [OUT_DIM, OUT_DIM+4096)   : transpose x -> xT bf16 [IN_DIM][BATCH]
// Tables: packed ptab[o][32] (16 uints = u16 idx pairs, 16 uints = bf16 w
// pairs; 128 B/row -> 32 SGPRs per o in spmm) + unpacked idx/w for fallback.
// ---------------------------------------------------------------------------
__global__ __launch_bounds__(256)
void prep_kernel(const float* __restrict__ weight,
                 const int*   __restrict__ mask,
                 const float* __restrict__ x,
                 unsigned*    __restrict__ ptab,
                 int*         __restrict__ idx_tab,
                 float*       __restrict__ w_tab,
                 unsigned short* __restrict__ xT) {
    __shared__ float tile[64][65];        // transpose tile; aliased as scan[]
    int* scan = (int*)&tile[0][0];
    const int t = threadIdx.x;

    if (blockIdx.x < OUT_DIM) {
        // ---- compress: one block per output row ----
        const int o = blockIdx.x;
        const int* mrow = mask + (size_t)o * IN_DIM;
        const int  base = t * 16;

        int m[16];
        const int4* m4 = (const int4*)(mrow + base);
        #pragma unroll
        for (int j = 0; j < 4; ++j) {
            int4 v = m4[j];
            m[j*4+0] = v.x; m[j*4+1] = v.y; m[j*4+2] = v.z; m[j*4+3] = v.w;
        }
        int c = 0;
        #pragma unroll
        for (int j = 0; j < 16; ++j) c += (m[j] != 0);

        scan[t] = c;
        __syncthreads();
        for (int off = 1; off < 256; off <<= 1) {
            int add = (t >= off) ? scan[t - off] : 0;
            __syncthreads();
            scan[t] += add;
            __syncthreads();
        }
        int pos = scan[t] - c;            // exclusive prefix
        for (int j = 0; j < 16; ++j) {
            if (m[j] != 0) {
                int   idx = base + j;
                float w   = weight[(size_t)o * IN_DIM + idx];
                idx_tab[o * NACT + pos] = idx;
                w_tab [o * NACT + pos] = w;
                // packed: u16 idx at slot pos, bf16 w at slot 32+pos
                unsigned short* pt = (unsigned short*)(ptab + (size_t)o * 32);
                pt[pos]      = (unsigned short)idx;
                pt[32 + pos] = f2bf(w);
                ++pos;
            }
        }
    } else {
        // ---- transpose + bf16 quantize: 64x64 tile ----
        const int q  = blockIdx.x - OUT_DIM;
        const int bi = q & 63;            // batch tile
        const int bj = q >> 6;            // in-dim tile
        {
            const int c  = (t & 15) * 4;
            const int r0 = t >> 4;
            #pragma unroll
            for (int p = 0; p < 4; ++p) {
                int r = r0 + p * 16;
                float4 v = *(const float4*)(x + (size_t)(bi*64 + r) * IN_DIM + bj*64 + c);
                tile[r][c+0] = v.x; tile[r][c+1] = v.y;
                tile[r][c+2] = v.z; tile[r][c+3] = v.w;
            }
        }
        __syncthreads();
        {
            const int b4 = (t & 15) * 4;
            const int j0 = t >> 4;
            #pragma unroll
            for (int p = 0; p < 4; ++p) {
                int j = j0 + p * 16;
                u16x4 v = { f2bf(tile[b4+0][j]), f2bf(tile[b4+1][j]),
                            f2bf(tile[b4+2][j]), f2bf(tile[b4+3][j]) };
                *(u16x4*)(xT + (size_t)(bj*64 + j) * BATCH + bi*64 + b4) = v;
            }
        }
    }
}

// ---------------------------------------------------------------------------
// Main sparse matmul — exact r10 geometry (proven best) + packed tables.
// Block = 128 threads; thread t = batches (2t, 2t+1) x 16 outputs.
// Slab = 256 batches x 4096 rows x 2B = 2 MB, L2-resident (r8/r10 FETCH
// ~= compulsory; r9 proved plain stores re-pollute -> keep nt + restage).
// Tables PACKED to 32 SGPRs/o (u16 idx pairs + bf16 w pairs): r10's 64
// SGPRs/o + 96-SGPR budget fit only ONE o-table -> each o began with a
// serialized ~300cy s_load wait. Packed, TWO o-tables fit -> unroll 2
// genuinely overlaps table-fetch(o+1) with gathers(o).
// Unpack is SALU; FMA reads w directly from SGPR (1-SGPR-operand rule).
// Store: nt + two-pass LDS restage L[128][17] (8.7 KB, r10-proven).
// Grid = 16 slabs x 256 o-tiles; swizzle: each XCD sweeps o-tiles slab-major.
// ---------------------------------------------------------------------------
__global__ __launch_bounds__(128)
void spmm_kernel(const unsigned short* __restrict__ xT,
                 const unsigned* __restrict__ ptab,
                 const float* __restrict__ bias,
                 float*       __restrict__ out) {
    const int t   = threadIdx.x;          // 0..127
    const int bid = blockIdx.x;           // 4096 blocks
    const int v    = (bid & 7) * 512 + (bid >> 3);   // bijective XCD swizzle
    const int slab = v >> 8;              // 0..15 (slab-major per XCD)
    const int ot   = v & 255;             // o-tile minor
    const int o0   = ot * 16;
    const int b0   = slab * 256;          // slab batch base
    const int bl   = t * 2;               // batch-local (even)

    const unsigned* xTd = (const unsigned*)xT;     // dword view (2 bf16/dword)
    const int bl2 = (b0 >> 1) + t;        // this thread's dword column

    float acc0[16], acc1[16];
    #pragma unroll 2
    for (int o = 0; o < 16; ++o) {
        const unsigned* tp = ptab + (size_t)(o0 + o) * 32;     // wave-uniform
        float a00 = 0.f, a01 = 0.f, a10 = 0.f, a11 = 0.f;
        #pragma unroll
        for (int kk = 0; kk < 16; ++kk) {
            unsigned ipk = __builtin_amdgcn_readfirstlane(tp[kk]);      // SGPR
            unsigned wpk = __builtin_amdgcn_readfirstlane(tp[16 + kk]); // SGPR
            int r0 = (int)(ipk & 0xFFFFu);          // SALU unpack
            int r1 = (int)(ipk >> 16);
            float w0 = __uint_as_float(wpk << 16);          // SALU
            float w1 = __uint_as_float(wpk & 0xFFFF0000u);  // SALU
            unsigned u0 = xTd[(size_t)r0 * (BATCH/2) + bl2];   // saddr + voff
            unsigned u1 = xTd[(size_t)r1 * (BATCH/2) + bl2];
            a00 = fmaf(w0, __uint_as_float(u0 << 16),         a00);
            a01 = fmaf(w0, __uint_as_float(u0 & 0xFFFF0000u), a01);
            a10 = fmaf(w1, __uint_as_float(u1 << 16),         a10);
            a11 = fmaf(w1, __uint_as_float(u1 & 0xFFFF0000u), a11);
        }
        const float bo = bias[o0 + o];
        acc0[o] = (a00 + a10) - bo;
        acc1[o] = (a01 + a11) - bo;
    }

    // ---- two-pass restage through LDS for full-line nt stores ----
    __shared__ float L[128 * 17];         // 8.7 KB: half-slab at a time
    #pragma unroll
    for (int h = 0; h < 2; ++h) {
        if ((t >> 6) == h) {              // wave-uniform branch
            const int r = bl & 127;       // row within half-slab
            #pragma unroll
            for (int o = 0; o < 16; ++o) {
                L[(r + 0) * 17 + o] = acc0[o];
                L[(r + 1) * 17 + o] = acc1[o];
            }
        }
        __syncthreads();
        const int rr = t >> 2;            // 0..31
        const int c  = (t & 3) * 4;       // 16B sub-line
        #pragma unroll
        for (int p = 0; p < 4; ++p) {
            int r = rr + p * 32;          // 0..127
            f32x4 rv = { L[r*17 + c+0], L[r*17 + c+1],
                         L[r*17 + c+2], L[r*17 + c+3] };
            __builtin_nontemporal_store(rv,
                (f32x4*)(out + (size_t)(b0 + h*128 + r) * OUT_DIM + o0 + c));
        }
        __syncthreads();                  // L reused by next pass
    }
}

// ---------------------------------------------------------------------------
// Fallback A (ws >= table only): gathers from x directly (uncoalesced, correct).
// ---------------------------------------------------------------------------
__global__ __launch_bounds__(256)
void spmm_noT_kernel(const float* __restrict__ x,
                     const int*   __restrict__ idx_tab,
                     const float* __restrict__ w_tab,
                     const float* __restrict__ bias,
                     float*       __restrict__ out) {
    const int t   = threadIdx.x;
    const int bid = blockIdx.x;           // 4096 blocks
    const int slab = bid >> 8;
    const int ot   = bid & 255;
    const int o0   = ot * 16;
    const int b    = slab * 256 + t;

    float acc[16];
    #pragma unroll 1
    for (int o = 0; o < 16; ++o) {
        const int*   ip = idx_tab + (size_t)(o0 + o) * NACT;
        const float* wp = w_tab   + (size_t)(o0 + o) * NACT;
        float a = 0.f;
        for (int k = 0; k < NACT; ++k)
            a = fmaf(wp[k], x[(size_t)b * IN_DIM + ip[k]], a);
        acc[o] = a - bias[o0 + o];
    }
    float* op = out + (size_t)b * OUT_DIM + o0;
    #pragma unroll
    for (int q = 0; q < 4; ++q) {
        float4 r; r.x = acc[q*4+0]; r.y = acc[q*4+1];
                  r.z = acc[q*4+2]; r.w = acc[q*4+3];
        *(float4*)(op + q*4) = r;
    }
}

// ---------------------------------------------------------------------------
// Fallback B (tiny ws): block per output row; inline compress into LDS.
// ---------------------------------------------------------------------------
__global__ __launch_bounds__(256)
void naive_kernel(const float* __restrict__ x,
                  const float* __restrict__ weight,
                  const float* __restrict__ bias,
                  const int*   __restrict__ mask,
                  float*       __restrict__ out) {
    const int o = blockIdx.x;
    const int t = threadIdx.x;
    __shared__ int   scan[256];
    __shared__ int   sidx[NACT];
    __shared__ float sw[NACT];

    const int* mrow = mask + (size_t)o * IN_DIM;
    const int  base = t * 16;
    int c = 0;
    #pragma unroll
    for (int j = 0; j < 16; ++j) c += (mrow[base + j] != 0);
    scan[t] = c;
    __syncthreads();
    for (int off = 1; off < 256; off <<= 1) {
        int add = (t >= off) ? scan[t - off] : 0;
        __syncthreads();
        scan[t] += add;
        __syncthreads();
    }
    int pos = scan[t] - c;
    for (int j = 0; j < 16; ++j) {
        if (mrow[base + j] != 0) {
            sidx[pos] = base + j;
            sw[pos]   = weight[(size_t)o * IN_DIM + base + j];
            ++pos;
        }
    }
    __syncthreads();
    const float bo = bias[o];
    for (int b = t; b < BATCH; b += 256) {
        float a = 0.f;
        #pragma unroll
        for (int k = 0; k < NACT; ++k)
            a = fmaf(sw[k], x[(size_t)b * IN_DIM + sidx[k]], a);
        out[(size_t)b * OUT_DIM + o] = a - bo;
    }
}

// ---------------------------------------------------------------------------
extern "C" void kernel_launch(void* const* d_in, const int* in_sizes, int n_in,
                              void* d_out, int out_size, void* d_ws, size_t ws_size,
                              hipStream_t stream) {
    const float* x      = (const float*)d_in[0];
    const float* weight = (const float*)d_in[1];
    const float* bias   = (const float*)d_in[2];
    const int*   mask   = (const int*)  d_in[3];
    float* out = (float*)d_out;

    const size_t PTAB_BYTES = (size_t)OUT_DIM * 32 * sizeof(unsigned);             // 0.5 MB
    const size_t TAB_BYTES  = (size_t)OUT_DIM * NACT * (sizeof(int) + sizeof(float)); // 1 MB
    const size_t XT_BYTES   = (size_t)IN_DIM * BATCH * sizeof(unsigned short);     // 32 MB
    const size_t NEED_FULL  = PTAB_BYTES + TAB_BYTES + XT_BYTES;

    unsigned* ptab    = (unsigned*)d_ws;
    int*      idx_tab = (int*)  ((char*)d_ws + PTAB_BYTES);
    float*    w_tab   = (float*)((char*)d_ws + PTAB_BYTES + (size_t)OUT_DIM * NACT * sizeof(int));

    if (ws_size >= NEED_FULL) {
        unsigned short* xT = (unsigned short*)((char*)d_ws + PTAB_BYTES + TAB_BYTES);

        prep_kernel<<<OUT_DIM + (BATCH/64)*(IN_DIM/64), 256, 0, stream>>>(
            weight, mask, x, ptab, idx_tab, w_tab, xT);
        spmm_kernel<<<4096, 128, 0, stream>>>(xT, ptab, bias, out);
    } else if (ws_size >= PTAB_BYTES + TAB_BYTES) {
        prep_kernel<<<OUT_DIM, 256, 0, stream>>>(
            weight, mask, x, ptab, idx_tab, w_tab, (unsigned short*)nullptr);
        spmm_noT_kernel<<<4096, 256, 0, stream>>>(x, idx_tab, w_tab, bias, out);
    } else {
        naive_kernel<<<OUT_DIM, 256, 0, stream>>>(x, weight, bias, mask, out);
    }
}